// Round 9
// baseline (63.329 us; speedup 1.0000x reference)
//
#include <hip/hip_runtime.h>
#include <math.h>

namespace {

constexpr int Bn = 8;
constexpr int Hn = 256;
constexpr int Wn = 256;
constexpr int HW = Hn * Wn;       // 65536
constexpr int Ntot = Bn * HW;     // 524288
constexpr int NBH = Bn * Hn;      // 2048 blocks for kAW / kH
constexpr float INF_F = 131138.0f; // sum(n*n for n in shape)+1
constexpr float EPSv = 1e-6f;

// 256-thread block sum; returns full sum to all threads. Fixed order -> deterministic.
__device__ __forceinline__ float blkred(float v, float* sm) {
    #pragma unroll
    for (int o = 32; o > 0; o >>= 1) v += __shfl_down(v, o, 64);
    int lane = threadIdx.x & 63, wid = threadIdx.x >> 6;
    __syncthreads();
    if (lane == 0) sm[wid] = v;
    __syncthreads();
    return sm[0] + sm[1] + sm[2] + sm[3];
}

// Thread-per-i exact 1D DT over a 256-line staged in LDS as u[j]=f[j]+j^2:
// res(i) = i^2 + min_j (u[j] + (-2i)*j). All intermediates exact integers
// (<2^24) -> bit-identical to the reference's brute force. All lanes read the
// same u4[q] -> wave-uniform broadcast ds_read_b128. Two min chains; the
// fminf pairs fuse to v_min3_f32 (6 VALU/q).
__device__ __forceinline__ float dt_thread(const float* __restrict__ u, int i) {
    const float4* u4 = reinterpret_cast<const float4*>(u);
    float ni2 = -2.0f * (float)i;
    float mA = 3.0e38f, mB = 3.0e38f;
    float jb = 0.f;
    #pragma unroll 8
    for (int q = 0; q < 64; ++q) {
        float4 uu = u4[q];
        mA = fminf(fminf(mA, fmaf(ni2, jb, uu.x)),
                   fmaf(ni2, jb + 1.f, uu.y));
        mB = fminf(fminf(mB, fmaf(ni2, jb + 2.f, uu.z)),
                   fmaf(ni2, jb + 3.f, uu.w));
        jb += 4.f;
    }
    return fminf(mA, mB) + (float)i * (float)i;
}

// Fused A+W+T: block = one (b,h) row (2048 blocks, 8/CU). Per thread (w):
// elementwise partials for own (b,h,w), axis-B DT for own b (all 8 masks at
// (h,w); tg re-read 8x, L2/L3-resident), W-DT thread-per-i, then TRANSPOSED
// scatter store of gT. Also arms kH's election counter.
__global__ __launch_bounds__(256) void kAW(const float* __restrict__ lg,
                                           const float* __restrict__ tg,
                                           float* __restrict__ gT,
                                           float* __restrict__ pa,
                                           unsigned int* __restrict__ cnt) {
    if (blockIdx.x == 0 && threadIdx.x == 0) *cnt = 0u;
    int blk = blockIdx.x;            // b*Hn + h
    int b = blk >> 8, h = blk & 255;
    int w = threadIdx.x;
    int t = h * Wn + w;
    float x = lg[(size_t)b * HW + t];
    float tv = 0.f;
    float m = 3.0e38f;
    #pragma unroll
    for (int j = 0; j < Bn; ++j) {   // coalesced plane reads
        float tj = tg[(size_t)j * HW + t];
        if (j == b) tv = tj;
        float fv = (tj > 0.5f) ? INF_F : 0.f;
        int d = b - j;
        m = fminf(m, fv + (float)(d * d));
    }
    float p  = 1.f / (1.f + expf(-x));
    float sp = p, st = tv, spt = p * tv;
    float ce = fmaxf(x, 0.f) - x * tv + log1pf(expf(-fabsf(x)));
    float pt = p * tv + (1.f - p) * (1.f - tv);
    float om = 1.f - pt;
    float fo = 0.25f * om * om * ce;         // ALPHA=0.25, GAMMA=2

    __shared__ __align__(16) float u[Wn];
    __shared__ float sm[4];
    u[w] = m + (float)w * (float)w;          // u = f + w^2
    __syncthreads();
    float res = dt_thread(u, w);
    gT[((size_t)b * Wn + w) * Hn + h] = res; // transposed scatter (4B, 1KB stride)

    sp  = blkred(sp, sm);
    st  = blkred(st, sm);
    spt = blkred(spt, sm);
    fo  = blkred(fo, sm);
    if (threadIdx.x == 0) {
        float* o = pa + blk * 4;
        o[0] = sp; o[1] = st; o[2] = spt; o[3] = fo;
    }
}

// Kernel H: block = one (b,w) column line (2048 blocks). Coalesced gT reads,
// thread-per-i DT, fused sqrt * (1-p)^2 + block reduce. The LAST-ARRIVING
// block performs the final combine (fixed index order -> bit-deterministic
// regardless of which block is elected) and re-arms the counter.
__global__ __launch_bounds__(256) void kH(const float* __restrict__ gT,
                                          const float* __restrict__ lg,
                                          const float* __restrict__ pa,
                                          float* __restrict__ bp,
                                          unsigned int* __restrict__ cnt,
                                          float* __restrict__ out) {
    int blk = blockIdx.x;            // b*Wn + w
    int b = blk >> 8, w = blk & 255;
    int i = threadIdx.x;             // h
    __shared__ __align__(16) float u[Hn];
    __shared__ float sm[4];
    __shared__ unsigned int tick;
    u[i] = gT[(size_t)blk * Hn + i] + (float)i * (float)i;
    float x = lg[(size_t)b * HW + i * Wn + w];  // strided scalar, issued early
    __syncthreads();
    float res = dt_thread(u, i);
    float s = 1.f / (1.f + expf(x));            // = 1 - sigmoid(x)
    float acc = sqrtf(res) * s * s;
    acc = blkred(acc, sm);
    if (i == 0) {
        bp[blk] = acc;
        __threadfence();                 // release bp before taking ticket
        tick = atomicAdd(cnt, 1u);
    }
    __syncthreads();
    if (tick == (unsigned int)(NBH - 1)) {
        __threadfence();                 // acquire all blocks' bp/pa
        int t = threadIdx.x;
        float sp = 0.f, st = 0.f, spt = 0.f, fo = 0.f, bs = 0.f;
        #pragma unroll
        for (int k = 0; k < 8; ++k) {
            const float* o = pa + (size_t)(t + 256 * k) * 4;
            sp += o[0]; st += o[1]; spt += o[2]; fo += o[3];
            bs += bp[t + 256 * k];
        }
        sp  = blkred(sp, sm);
        st  = blkred(st, sm);
        spt = blkred(spt, sm);
        fo  = blkred(fo, sm);
        bs  = blkred(bs, sm);
        if (t == 0) {
            float dice = 1.f - (2.f * spt + EPSv) / (sp + st + EPSv);
            float boundary = bs / (float)Ntot;
            float focal = fo / (float)Ntot;
            out[0] = 1.0f * dice + 0.5f * boundary + 1.0f * focal;
            *cnt = 0u;                   // re-arm for next graph replay
        }
    }
}

} // namespace

extern "C" void kernel_launch(void* const* d_in, const int* in_sizes, int n_in,
                              void* d_out, int out_size, void* d_ws, size_t ws_size,
                              hipStream_t stream) {
    const float* lg = (const float*)d_in[0];   // logits  [8,1,256,256] f32
    const float* tg = (const float*)d_in[1];   // targets [8,1,256,256] f32
    float* ws = (float*)d_ws;
    float* gT = ws;                        // [b][w][h] post B+W DT, 2 MB
    float* pa = ws + Ntot;                 // 2048 blocks * 4 partials
    float* bp = ws + Ntot + 4 * NBH;       // 2048 boundary partials
    unsigned int* cnt = (unsigned int*)(ws + Ntot + 5 * NBH);

    kAW<<<NBH, 256, 0, stream>>>(lg, tg, gT, pa, cnt);
    kH<<<NBH, 256, 0, stream>>>(gT, lg, pa, bp, cnt, (float*)d_out);
}

// Round 10
// 30.016 us; speedup vs baseline: 2.1098x; 2.1098x over previous
//
#include <hip/hip_runtime.h>
#include <math.h>

namespace {

constexpr int Bn = 8;
constexpr int Hn = 256;
constexpr int Wn = 256;
constexpr int HW = Hn * Wn;       // 65536
constexpr int Ntot = Bn * HW;     // 524288
constexpr int NAW = Bn * 64;      // 512 kAW blocks (4 rows each)
constexpr int NBH = Bn * Wn;      // 2048 kH blocks
constexpr float INF_F = 131138.0f; // sum(n*n for n in shape)+1
constexpr float EPSv = 1e-6f;

// 256-thread block sum; returns full sum to all threads. Fixed order -> deterministic.
__device__ __forceinline__ float blkred(float v, float* sm) {
    #pragma unroll
    for (int o = 32; o > 0; o >>= 1) v += __shfl_down(v, o, 64);
    int lane = threadIdx.x & 63, wid = threadIdx.x >> 6;
    __syncthreads();
    if (lane == 0) sm[wid] = v;
    __syncthreads();
    return sm[0] + sm[1] + sm[2] + sm[3];
}

__device__ __forceinline__ float getc(const float4& v, int r) {
    return r == 0 ? v.x : r == 1 ? v.y : r == 2 ? v.z : v.w;
}

// Wave-cooperative exact 1D DT over a 256-line staged in LDS as
// u[j] = f[j] + j^2:  res(i) = i^2 + min_j (u[j] + (-2i)*j).
// All intermediates exact integers (<2^24) -> bit-identical to the
// reference's brute force. Lane l owns i in {4l..4l+3}; wave-uniform
// broadcast ds_read_b128; fminf pairs fuse to v_min3_f32.
__device__ __forceinline__ void dt_wave4(const float* __restrict__ u,
                                         int lane, float res[4]) {
    const float4* u4 = reinterpret_cast<const float4*>(u);
    float fi[4], ni2[4], mA[4], mB[4];
    #pragma unroll
    for (int r = 0; r < 4; ++r) {
        fi[r]  = (float)(4 * lane + r);
        ni2[r] = -2.0f * fi[r];
        mA[r] = 3.0e38f; mB[r] = 3.0e38f;
    }
    float jb = 0.f;
    #pragma unroll 8
    for (int q = 0; q < 64; ++q) {
        float4 uu = u4[q];             // wave-uniform broadcast read
        float j0 = jb, j1 = jb + 1.f, j2 = jb + 2.f, j3 = jb + 3.f;
        jb += 4.f;
        #pragma unroll
        for (int r = 0; r < 4; ++r) {
            mA[r] = fminf(fminf(mA[r], fmaf(ni2[r], j0, uu.x)),
                          fmaf(ni2[r], j1, uu.y));   // -> v_min3_f32
            mB[r] = fminf(fminf(mB[r], fmaf(ni2[r], j2, uu.z)),
                          fmaf(ni2[r], j3, uu.w));
        }
    }
    #pragma unroll
    for (int r = 0; r < 4; ++r)
        res[r] = fminf(mA[r], mB[r]) + fi[r] * fi[r];
}

// Thread-per-i variant (kH): all lanes broadcast-read the same u4[q].
__device__ __forceinline__ float dt_thread(const float* __restrict__ u, int i) {
    const float4* u4 = reinterpret_cast<const float4*>(u);
    float ni2 = -2.0f * (float)i;
    float mA = 3.0e38f, mB = 3.0e38f;
    float jb = 0.f;
    #pragma unroll 8
    for (int q = 0; q < 64; ++q) {
        float4 uu = u4[q];
        mA = fminf(fminf(mA, fmaf(ni2, jb, uu.x)),
                   fmaf(ni2, jb + 1.f, uu.y));
        mB = fminf(fminf(mB, fmaf(ni2, jb + 2.f, uu.z)),
                   fmaf(ni2, jb + 3.f, uu.w));
        jb += 4.f;
    }
    return fminf(mA, mB) + (float)i * (float)i;
}

// Fused A+W+T: block = 4 rows of one batch (512 blocks, 2/CU, 8 waves/CU).
// Wave wv owns row h0+wv. Per thread: 4 pixels (float4 lg/tg loads) of
// elementwise partials + axis-B DT for own b, wave-cooperative W-DT, then
// LDS transpose -> float4 transposed stores (16B chunks, 4x less write
// amplification than 4B scatter).
__global__ __launch_bounds__(256) void kAW(const float* __restrict__ lg,
                                           const float* __restrict__ tg,
                                           float* __restrict__ gT,
                                           float* __restrict__ pa) {
    __shared__ __align__(16) float uL[4][Wn];
    __shared__ __align__(16) float vL[4][Wn];
    __shared__ float sm[4];
    int tid = threadIdx.x, wv = tid >> 6, lane = tid & 63;
    int blk = blockIdx.x;            // b*64 + hg
    int b = blk >> 6;
    int h0 = (blk & 63) * 4;
    int h = h0 + wv;
    int w4 = lane * 4;

    float4 xg = *reinterpret_cast<const float4*>(lg + (size_t)b * HW + h * Wn + w4);
    float4 tgv[Bn];
    #pragma unroll
    for (int j = 0; j < Bn; ++j)
        tgv[j] = *reinterpret_cast<const float4*>(tg + (size_t)j * HW + h * Wn + w4);
    float d2[Bn];
    #pragma unroll
    for (int j = 0; j < Bn; ++j) { int e = b - j; d2[j] = (float)(e * e); }

    float sp = 0.f, st = 0.f, spt = 0.f, fo = 0.f;
    float uv[4];
    #pragma unroll
    for (int r = 0; r < 4; ++r) {
        float x  = getc(xg, r);
        float tv = getc(tgv[b], r);
        float p  = 1.f / (1.f + expf(-x));
        sp  += p;
        st  += tv;
        spt += p * tv;
        float ce = fmaxf(x, 0.f) - x * tv + log1pf(expf(-fabsf(x)));
        float pt = p * tv + (1.f - p) * (1.f - tv);
        float om = 1.f - pt;
        fo += 0.25f * om * om * ce;          // ALPHA=0.25, GAMMA=2
        float m = 3.0e38f;
        #pragma unroll
        for (int j = 0; j < Bn; ++j) {       // axis-B DT (exact)
            float fv = getc(tgv[j], r) > 0.5f ? INF_F : 0.f;
            m = fminf(m, fv + d2[j]);
        }
        float wF = (float)(w4 + r);
        uv[r] = m + wF * wF;                 // u = f + w^2
    }
    *reinterpret_cast<float4*>(&uL[wv][w4]) = make_float4(uv[0], uv[1], uv[2], uv[3]);
    // wave-local LDS dep (write->read same wave's row): in-order, no barrier
    float res[4];
    dt_wave4(uL[wv], lane, res);
    *reinterpret_cast<float4*>(&vL[wv][w4]) = make_float4(res[0], res[1], res[2], res[3]);

    sp  = blkred(sp, sm);    // first internal __syncthreads makes vL visible
    st  = blkred(st, sm);
    spt = blkred(spt, sm);
    fo  = blkred(fo, sm);
    if (tid == 0) {
        float* o = pa + blk * 4;
        o[0] = sp; o[1] = st; o[2] = spt; o[3] = fo;
    }
    // transposed store: thread tid = w; 4 h-values -> one 16B chunk
    float4 gv = make_float4(vL[0][tid], vL[1][tid], vL[2][tid], vL[3][tid]);
    *reinterpret_cast<float4*>(gT + ((size_t)b * Wn + tid) * Hn + h0) = gv;
}

// Kernel H: block = one (b,w) column line (2048 blocks, 8/CU). Coalesced gT
// reads, thread-per-i DT, fused sqrt * (1-p)^2 (strided lg scalar,
// L2/L3-resident) + block reduce. (Identical to R8's proven version.)
__global__ __launch_bounds__(256) void kH(const float* __restrict__ gT,
                                          const float* __restrict__ lg,
                                          float* __restrict__ bp) {
    int blk = blockIdx.x;            // b*Wn + w
    int b = blk >> 8, w = blk & 255;
    int i = threadIdx.x;             // h
    __shared__ __align__(16) float u[Hn];
    __shared__ float sm[4];
    u[i] = gT[(size_t)blk * Hn + i] + (float)i * (float)i;
    float x = lg[(size_t)b * HW + i * Wn + w];  // strided scalar, issued early
    __syncthreads();
    float res = dt_thread(u, i);
    float s = 1.f / (1.f + expf(x));            // = 1 - sigmoid(x)
    float acc = sqrtf(res) * s * s;
    acc = blkred(acc, sm);
    if (i == 0) bp[blk] = acc;
}

// Kernel D: final combine. One block. pa: 512 entries; bp: 2048.
__global__ __launch_bounds__(256) void kD(const float* __restrict__ pa,
                                          const float* __restrict__ bp,
                                          float* __restrict__ out) {
    __shared__ float sm[4];
    int t = threadIdx.x;
    float sp = 0.f, st = 0.f, spt = 0.f, fo = 0.f, bs = 0.f;
    #pragma unroll
    for (int k = 0; k < 2; ++k) {
        const float* o = pa + (size_t)(t + 256 * k) * 4;
        sp += o[0]; st += o[1]; spt += o[2]; fo += o[3];
    }
    #pragma unroll
    for (int k = 0; k < 8; ++k) bs += bp[t + 256 * k];
    sp  = blkred(sp, sm);
    st  = blkred(st, sm);
    spt = blkred(spt, sm);
    fo  = blkred(fo, sm);
    bs  = blkred(bs, sm);
    if (t == 0) {
        float dice = 1.f - (2.f * spt + EPSv) / (sp + st + EPSv);
        float boundary = bs / (float)Ntot;
        float focal = fo / (float)Ntot;
        out[0] = 1.0f * dice + 0.5f * boundary + 1.0f * focal;
    }
}

} // namespace

extern "C" void kernel_launch(void* const* d_in, const int* in_sizes, int n_in,
                              void* d_out, int out_size, void* d_ws, size_t ws_size,
                              hipStream_t stream) {
    const float* lg = (const float*)d_in[0];   // logits  [8,1,256,256] f32
    const float* tg = (const float*)d_in[1];   // targets [8,1,256,256] f32
    float* ws = (float*)d_ws;
    float* gT = ws;                        // [b][w][h] post B+W DT, 2 MB
    float* pa = ws + Ntot;                 // 512 blocks * 4 partials
    float* bp = ws + Ntot + 4 * NAW;       // 2048 boundary partials

    kAW<<<NAW, 256, 0, stream>>>(lg, tg, gT, pa);
    kH<<<NBH, 256, 0, stream>>>(gT, lg, bp);
    kD<<<1, 256, 0, stream>>>(pa, bp, (float*)d_out);
}